// Round 1
// baseline (8277.135 us; speedup 1.0000x reference)
//
#include <hip/hip_runtime.h>
#include <hip/hip_bf16.h>
#include <math.h>

#define CC 768
#define TT 512
#define BB 2
#define HH 12
#define KV 64
#define LL 6
#define VV 50304
#define DFF 2688
#define MM (BB*TT)   // 1024

// ---------------- block reduce ----------------
__device__ __forceinline__ float block_reduce_sum256(float v, float* red) {
    int tid = threadIdx.x;
    red[tid] = v; __syncthreads();
    #pragma unroll
    for (int s = 128; s > 0; s >>= 1) {
        if (tid < s) red[tid] += red[tid + s];
        __syncthreads();
    }
    float r = red[0];
    __syncthreads();
    return r;
}

// ---------------- LayerNorm over C=768 (optionally gathering embed rows) ----------------
// grid = MM blocks, 256 threads; each thread handles c = tid, tid+256, tid+512
__global__ __launch_bounds__(256) void ln_embed_kernel(
        const float* __restrict__ in, const int* __restrict__ tokens,
        const float* __restrict__ s, const float* __restrict__ b,
        float* __restrict__ out) {
    __shared__ float red[256];
    int row = blockIdx.x;
    int tid = threadIdx.x;
    const float* x = in + (size_t)(tokens ? tokens[row] : row) * CC;
    float x0 = x[tid], x1 = x[tid + 256], x2 = x[tid + 512];
    float total = block_reduce_sum256(x0 + x1 + x2, red);
    float mean = total * (1.f / 768.f);
    float d0 = x0 - mean, d1 = x1 - mean, d2 = x2 - mean;
    float var = block_reduce_sum256(d0*d0 + d1*d1 + d2*d2, red) * (1.f / 768.f);
    float inv = rsqrtf(var + 1e-5f);
    float* o = out + (size_t)row * CC;
    o[tid]       = d0 * inv * s[tid]       + b[tid];
    o[tid + 256] = d1 * inv * s[tid + 256] + b[tid + 256];
    o[tid + 512] = d2 * inv * s[tid + 512] + b[tid + 512];
}

// ---------------- lerp kernels (token-shift mixing) ----------------
// idx over MM*CC; xs = shifted row (zero at t==0 within each batch)
__global__ __launch_bounds__(256) void lerp4_kernel(
        const float* __restrict__ ln,
        const float* __restrict__ tr, const float* __restrict__ tk,
        const float* __restrict__ tv, const float* __restrict__ tg,
        float* __restrict__ xr, float* __restrict__ xk,
        float* __restrict__ xv, float* __restrict__ xg) {
    int idx = blockIdx.x * 256 + threadIdx.x;
    int c = idx % CC;
    int row = idx / CC;
    int tl = row % TT;
    float x = ln[idx];
    float xs = (tl == 0) ? 0.f : ln[idx - CC];
    float d = xs - x;
    xr[idx] = fmaf(tr[c], d, x);
    xk[idx] = fmaf(tk[c], d, x);
    xv[idx] = fmaf(tv[c], d, x);
    xg[idx] = fmaf(tg[c], d, x);
}

__global__ __launch_bounds__(256) void lerp2_kernel(
        const float* __restrict__ ln,
        const float* __restrict__ ti, const float* __restrict__ tg,
        float* __restrict__ xi, float* __restrict__ xg) {
    int idx = blockIdx.x * 256 + threadIdx.x;
    int c = idx % CC;
    int row = idx / CC;
    int tl = row % TT;
    float x = ln[idx];
    float xs = (tl == 0) ? 0.f : ln[idx - CC];
    float d = xs - x;
    xi[idx] = fmaf(ti[c], d, x);
    xg[idx] = fmaf(tg[c], d, x);
}

// ---------------- fp32 GEMM: C = epi(A @ B^T) [*mul] [+res] ----------------
// A: M x K row-major; B: N x K row-major (so A @ B^T); tiles 128(M) x 64(N) x 16(K).
// mode: 0 = identity, 1 = relu^2, 2 = sigmoid
__global__ __launch_bounds__(256) void gemm_kernel(
        const float* __restrict__ A, const float* __restrict__ Bm,
        float* __restrict__ C, int M, int N, int K,
        int mode, const float* __restrict__ mul, const float* __restrict__ res) {
    __shared__ float As[16][132];
    __shared__ float Bs[16][68];
    int tid = threadIdx.x;
    int tx = tid & 15, ty = tid >> 4;
    int n0 = blockIdx.x * 64, m0 = blockIdx.y * 128;
    int kk = tid & 15, mr = tid >> 4;

    float acc[8][4];
    #pragma unroll
    for (int i = 0; i < 8; i++)
        #pragma unroll
        for (int j = 0; j < 4; j++) acc[i][j] = 0.f;

    for (int k0 = 0; k0 < K; k0 += 16) {
        #pragma unroll
        for (int i = 0; i < 8; i++)
            As[kk][mr + i*16] = A[(size_t)(m0 + mr + i*16) * K + k0 + kk];
        #pragma unroll
        for (int i = 0; i < 4; i++)
            Bs[kk][mr + i*16] = Bm[(size_t)(n0 + mr + i*16) * K + k0 + kk];
        __syncthreads();
        #pragma unroll
        for (int kq = 0; kq < 16; kq++) {
            float a[8], bb[4];
            #pragma unroll
            for (int i = 0; i < 8; i++) a[i] = As[kq][ty*8 + i];
            #pragma unroll
            for (int j = 0; j < 4; j++) bb[j] = Bs[kq][tx*4 + j];
            #pragma unroll
            for (int i = 0; i < 8; i++)
                #pragma unroll
                for (int j = 0; j < 4; j++)
                    acc[i][j] = fmaf(a[i], bb[j], acc[i][j]);
        }
        __syncthreads();
    }

    #pragma unroll
    for (int i = 0; i < 8; i++) {
        int row = m0 + ty*8 + i;
        int col = n0 + tx*4;
        size_t off = (size_t)row * N + col;
        float vv[4];
        #pragma unroll
        for (int j = 0; j < 4; j++) {
            float v = acc[i][j];
            if (mode == 1) { v = v > 0.f ? v : 0.f; v = v * v; }
            else if (mode == 2) { v = 1.f / (1.f + expf(-v)); }
            vv[j] = v;
        }
        if (mul) {
            const float4 mm = *(const float4*)(mul + off);
            vv[0] *= mm.x; vv[1] *= mm.y; vv[2] *= mm.z; vv[3] *= mm.w;
        }
        if (res) {
            const float4 rr = *(const float4*)(res + off);
            vv[0] += rr.x; vv[1] += rr.y; vv[2] += rr.z; vv[3] += rr.w;
        }
        *(float4*)(C + off) = make_float4(vv[0], vv[1], vv[2], vv[3]);
    }
}

// ---------------- WKV sequential scan ----------------
// grid = BB*HH blocks, 256 threads. thread: v = tid&63, kgroup = tid>>6 (16 k's each).
__global__ __launch_bounds__(256) void wkv_kernel(
        const float* __restrict__ r, const float* __restrict__ k,
        const float* __restrict__ v, const float* __restrict__ bonus,
        const float* __restrict__ decay, float* __restrict__ out) {
    int bh = blockIdx.x;
    int b = bh / HH, h = bh % HH;
    int tid = threadIdx.x;
    int vi = tid & 63;
    int kg = tid >> 6;   // 0..3

    float u_reg[16], w_reg[16], kv[16];
    #pragma unroll
    for (int i = 0; i < 16; i++) {
        int kidx = kg*16 + i;
        u_reg[i] = bonus[h*KV + kidx];
        w_reg[i] = expf(-expf(decay[h*KV + kidx]));
        kv[i] = 0.f;
    }

    __shared__ float sr[64], sk[64], sred[4][64];

    for (int t = 0; t < TT; t++) {
        size_t base = ((size_t)(b*TT + t) * HH + h) * KV;
        if (tid < 64) sr[tid] = r[base + tid];
        else if (tid < 128) sk[tid - 64] = k[base + tid - 64];
        float vval = v[base + vi];
        __syncthreads();
        float psum = 0.f;
        #pragma unroll
        for (int i = 0; i < 16; i++) {
            float a = sk[kg*16 + i] * vval;          // outer(k,v) element
            psum += sr[kg*16 + i] * fmaf(u_reg[i], a, kv[i]);
            kv[i] = fmaf(kv[i], w_reg[i], a);
        }
        sred[kg][vi] = psum;
        __syncthreads();
        if (kg == 0)
            out[base + vi] = sred[0][vi] + sred[1][vi] + sred[2][vi] + sred[3][vi];
    }
}

// ---------------- GroupNorm(eps=0.00064) * silu(g) ----------------
// grid = MM*HH blocks of 64 threads (one wave per group)
__global__ __launch_bounds__(64) void gn_silu_kernel(
        const float* __restrict__ wkvo, const float* __restrict__ g,
        const float* __restrict__ gs, const float* __restrict__ gb,
        float* __restrict__ out) {
    int gi = blockIdx.x;           // row*HH + h
    int vi = threadIdx.x;          // 0..63
    int h = gi % HH;
    int row = gi / HH;
    float val = wkvo[(size_t)gi * 64 + vi];
    float s1 = val;
    #pragma unroll
    for (int off = 32; off >= 1; off >>= 1) s1 += __shfl_xor(s1, off);
    float m = s1 * (1.f / 64.f);
    float d = val - m;
    float s2 = d * d;
    #pragma unroll
    for (int off = 32; off >= 1; off >>= 1) s2 += __shfl_xor(s2, off);
    float inv = rsqrtf(s2 * (1.f / 64.f) + 0.00064f);
    int c = h * 64 + vi;
    float gg = g[(size_t)row * CC + c];
    float sig = 1.f / (1.f + expf(-gg));
    out[(size_t)row * CC + c] = (d * inv * gs[c] + gb[c]) * (gg * sig);
}

// ---------------- host ----------------
extern "C" void kernel_launch(void* const* d_in, const int* in_sizes, int n_in,
                              void* d_out, int out_size, void* d_ws, size_t ws_size,
                              hipStream_t stream) {
    const int*   tokens    = (const int*)  d_in[0];
    const float* embed     = (const float*)d_in[1];
    const float* emb_ln_s  = (const float*)d_in[2];
    const float* emb_ln_b  = (const float*)d_in[3];
    const float* tm_ln_s   = (const float*)d_in[4];
    const float* tm_ln_b   = (const float*)d_in[5];
    const float* ts_r      = (const float*)d_in[6];
    const float* ts_k      = (const float*)d_in[7];
    const float* ts_v      = (const float*)d_in[8];
    const float* ts_g      = (const float*)d_in[9];
    const float* W_r       = (const float*)d_in[10];
    const float* W_k       = (const float*)d_in[11];
    const float* W_v       = (const float*)d_in[12];
    const float* W_g       = (const float*)d_in[13];
    const float* W_o       = (const float*)d_in[14];
    const float* bonus     = (const float*)d_in[15];
    const float* decay     = (const float*)d_in[16];
    const float* gn_s      = (const float*)d_in[17];
    const float* gn_b      = (const float*)d_in[18];
    const float* cm_ln_s   = (const float*)d_in[19];
    const float* cm_ln_b   = (const float*)d_in[20];
    const float* cm_ts_in  = (const float*)d_in[21];
    const float* cm_ts_g   = (const float*)d_in[22];
    const float* W_in      = (const float*)d_in[23];
    const float* W_out     = (const float*)d_in[24];
    const float* W_gate    = (const float*)d_in[25];
    const float* head_ln_s = (const float*)d_in[26];
    const float* head_ln_b = (const float*)d_in[27];
    const float* W_unembed = (const float*)d_in[28];

    float* ws = (float*)d_ws;
    size_t MC = (size_t)MM * CC;
    float* hbuf = ws; ws += MC;
    float* lnb  = ws; ws += MC;
    float* xr   = ws; ws += MC;
    float* xk   = ws; ws += MC;
    float* xv   = ws; ws += MC;
    float* xg   = ws; ws += MC;
    float* rb   = ws; ws += MC;
    float* kb   = ws; ws += MC;
    float* vb   = ws; ws += MC;
    float* gb   = ws; ws += MC;
    float* wkvo = ws; ws += MC;
    float* tmo  = ws; ws += MC;
    float* gate = ws; ws += MC;
    float* hid  = ws; ws += (size_t)MM * DFF;

    dim3 gLN(MM), b256(256);
    dim3 gLerp(MM * CC / 256);
    dim3 gGemmC(CC / 64, MM / 128);     // N=768
    dim3 gGemmF(DFF / 64, MM / 128);    // N=2688
    dim3 gGemmV(VV / 64, MM / 128);     // N=50304

    // embedding + LN
    ln_embed_kernel<<<gLN, b256, 0, stream>>>(embed, tokens, emb_ln_s, emb_ln_b, hbuf);

    for (int l = 0; l < LL; l++) {
        const float* Wr = W_r + (size_t)l * CC * CC;
        const float* Wk = W_k + (size_t)l * CC * CC;
        const float* Wv = W_v + (size_t)l * CC * CC;
        const float* Wg = W_g + (size_t)l * CC * CC;
        const float* Wo = W_o + (size_t)l * CC * CC;
        const float* Wi = W_in  + (size_t)l * DFF * CC;
        const float* Wu = W_out + (size_t)l * CC * DFF;
        const float* Wgt= W_gate+ (size_t)l * CC * CC;

        // ---- time mixer ----
        ln_embed_kernel<<<gLN, b256, 0, stream>>>(hbuf, nullptr, tm_ln_s + l*CC, tm_ln_b + l*CC, lnb);
        lerp4_kernel<<<gLerp, b256, 0, stream>>>(lnb, ts_r + l*CC, ts_k + l*CC, ts_v + l*CC, ts_g + l*CC,
                                                 xr, xk, xv, xg);
        gemm_kernel<<<gGemmC, b256, 0, stream>>>(xr, Wr, rb, MM, CC, CC, 0, nullptr, nullptr);
        gemm_kernel<<<gGemmC, b256, 0, stream>>>(xk, Wk, kb, MM, CC, CC, 0, nullptr, nullptr);
        gemm_kernel<<<gGemmC, b256, 0, stream>>>(xv, Wv, vb, MM, CC, CC, 0, nullptr, nullptr);
        gemm_kernel<<<gGemmC, b256, 0, stream>>>(xg, Wg, gb, MM, CC, CC, 0, nullptr, nullptr);
        wkv_kernel<<<dim3(BB*HH), b256, 0, stream>>>(rb, kb, vb, bonus + l*HH*KV, decay + l*HH*KV, wkvo);
        gn_silu_kernel<<<dim3(MM*HH), dim3(64), 0, stream>>>(wkvo, gb, gn_s + l*CC, gn_b + l*CC, tmo);
        // h = h + tmo @ Wo^T   (in-place residual)
        gemm_kernel<<<gGemmC, b256, 0, stream>>>(tmo, Wo, hbuf, MM, CC, CC, 0, nullptr, hbuf);

        // ---- channel mixer ----
        ln_embed_kernel<<<gLN, b256, 0, stream>>>(hbuf, nullptr, cm_ln_s + l*CC, cm_ln_b + l*CC, lnb);
        lerp2_kernel<<<gLerp, b256, 0, stream>>>(lnb, cm_ts_in + l*CC, cm_ts_g + l*CC, xr, xk);
        gemm_kernel<<<gGemmF, b256, 0, stream>>>(xr, Wi, hid, MM, DFF, CC, 1, nullptr, nullptr);   // relu^2
        gemm_kernel<<<gGemmC, b256, 0, stream>>>(xk, Wgt, gate, MM, CC, CC, 2, nullptr, nullptr);  // sigmoid
        // h = h + (hid @ Wout^T) * gate
        gemm_kernel<<<gGemmC, b256, 0, stream>>>(hid, Wu, hbuf, MM, CC, DFF, 0, gate, hbuf);
    }

    // head LN + unembed
    ln_embed_kernel<<<gLN, b256, 0, stream>>>(hbuf, nullptr, head_ln_s, head_ln_b, lnb);
    gemm_kernel<<<gGemmV, b256, 0, stream>>>(lnb, W_unembed, (float*)d_out, MM, VV, CC, 0, nullptr, nullptr);
}

// Round 2
// 3759.515 us; speedup vs baseline: 2.2016x; 2.2016x over previous
//
#include <hip/hip_runtime.h>
#include <hip/hip_bf16.h>
#include <math.h>

#define CC 768
#define TT 512
#define BB 2
#define HH 12
#define KV 64
#define LL 6
#define VV 50304
#define DFF 2688
#define MM (BB*TT)   // 1024

typedef unsigned short ushort_t;
typedef __attribute__((ext_vector_type(8))) short short8;
typedef __attribute__((ext_vector_type(4))) float floatx4;

__device__ __forceinline__ unsigned short f2b(float f) {
    union { float f; unsigned u; } v; v.f = f;
    unsigned r = (v.u + 0x7fffu + ((v.u >> 16) & 1u)) >> 16;
    return (unsigned short)r;
}

__device__ __forceinline__ void async16(const void* g, const void* l) {
    __builtin_amdgcn_global_load_lds((const __attribute__((address_space(1))) unsigned int*)g,
                                     (__attribute__((address_space(3))) unsigned int*)l, 16, 0, 0);
}

// ---------------- block reduce ----------------
__device__ __forceinline__ float block_reduce_sum256(float v, float* red) {
    int tid = threadIdx.x;
    red[tid] = v; __syncthreads();
    #pragma unroll
    for (int s = 128; s > 0; s >>= 1) {
        if (tid < s) red[tid] += red[tid + s];
        __syncthreads();
    }
    float r = red[0];
    __syncthreads();
    return r;
}

// ---------------- LayerNorm over C=768 (optionally gathering embed rows, optional bf16 out) ----
__global__ __launch_bounds__(256) void ln_kernel(
        const float* __restrict__ in, const int* __restrict__ tokens,
        const float* __restrict__ s, const float* __restrict__ b,
        float* __restrict__ out, unsigned short* __restrict__ outb) {
    __shared__ float red[256];
    int row = blockIdx.x;
    int tid = threadIdx.x;
    const float* x = in + (size_t)(tokens ? tokens[row] : row) * CC;
    float x0 = x[tid], x1 = x[tid + 256], x2 = x[tid + 512];
    float total = block_reduce_sum256(x0 + x1 + x2, red);
    float mean = total * (1.f / 768.f);
    float d0 = x0 - mean, d1 = x1 - mean, d2 = x2 - mean;
    float var = block_reduce_sum256(d0*d0 + d1*d1 + d2*d2, red) * (1.f / 768.f);
    float inv = rsqrtf(var + 1e-5f);
    float o0 = d0 * inv * s[tid]       + b[tid];
    float o1 = d1 * inv * s[tid + 256] + b[tid + 256];
    float o2 = d2 * inv * s[tid + 512] + b[tid + 512];
    float* o = out + (size_t)row * CC;
    o[tid] = o0; o[tid + 256] = o1; o[tid + 512] = o2;
    if (outb) {
        unsigned short* ob = outb + (size_t)row * CC;
        ob[tid] = f2b(o0); ob[tid + 256] = f2b(o1); ob[tid + 512] = f2b(o2);
    }
}

// ---------------- build A = [x, xs] bf16, [MM][1536] ----------------
__global__ __launch_bounds__(256) void build_a_kernel(
        const float* __restrict__ lnb, unsigned short* __restrict__ abuf) {
    int i = blockIdx.x * 256 + threadIdx.x;   // over MM*192 float4s
    int c4 = i % 192;
    int row = i / 192;
    float4 x = ((const float4*)lnb)[i];
    ushort4 o0; o0.x = f2b(x.x); o0.y = f2b(x.y); o0.z = f2b(x.z); o0.w = f2b(x.w);
    ((ushort4*)(abuf + (size_t)row * 1536))[c4] = o0;
    float4 xs;
    if ((row % TT) == 0) xs = make_float4(0.f, 0.f, 0.f, 0.f);
    else xs = ((const float4*)lnb)[i - 192];
    ushort4 o1; o1.x = f2b(xs.x); o1.y = f2b(xs.y); o1.z = f2b(xs.z); o1.w = f2b(xs.w);
    ((ushort4*)(abuf + (size_t)row * 1536 + 768))[c4] = o1;
}

// ---------------- weight convert fp32->bf16 ----------------
__global__ __launch_bounds__(256) void convertw_kernel(
        const float* __restrict__ src, unsigned short* __restrict__ dst, int n4) {
    int i = blockIdx.x * 256 + threadIdx.x;
    if (i >= n4) return;
    float4 v = ((const float4*)src)[i];
    ushort4 o; o.x = f2b(v.x); o.y = f2b(v.y); o.z = f2b(v.z); o.w = f2b(v.w);
    ((ushort4*)dst)[i] = o;
}

// ---------------- weight pack with lerp fold: dst[n][c]=W*(1-t), dst[n][K+c]=W*t ------------
__global__ __launch_bounds__(256) void packw_kernel(
        const float* __restrict__ W, const float* __restrict__ t,
        unsigned short* __restrict__ dst, int K, int n4) {
    int i = blockIdx.x * 256 + threadIdx.x;
    if (i >= n4) return;
    int K4 = K >> 2;
    int row = i / K4, c4 = i % K4;
    float4 w = ((const float4*)W)[i];
    float4 tv = ((const float4*)t)[c4];
    ushort4 a, bq;
    a.x = f2b(w.x * (1.f - tv.x)); a.y = f2b(w.y * (1.f - tv.y));
    a.z = f2b(w.z * (1.f - tv.z)); a.w = f2b(w.w * (1.f - tv.w));
    bq.x = f2b(w.x * tv.x); bq.y = f2b(w.y * tv.y);
    bq.z = f2b(w.z * tv.z); bq.w = f2b(w.w * tv.w);
    ushort4* drow = (ushort4*)(dst + (size_t)row * 2 * K);
    drow[c4] = a;
    ((ushort4*)(dst + (size_t)row * 2 * K + K))[c4] = bq;
}

// ---------------- bf16 MFMA GEMM: C = epi(A @ B^T) ----------------
// A: M x K bf16 row-major; B: N x K bf16 row-major. BM=128, BK=32, BN in {128,64}.
// 256 threads = 4 waves in 2x2; wave tile (64)x(BN/2); 16x16x32 MFMA frags.
// mode 0: Cf=acc (ld N); 1: Cf=acc+res; 2: Cf=acc*mul+res; 3: split at NS:
//   col<NS: Cb[row*NS+col]=bf16(relu(acc)^2); col>=NS: Cf[row*(N-NS)+col-NS]=sigmoid(acc)
template<int BN>
__global__ __launch_bounds__(256) void mfma_gemm_kernel(
        const unsigned short* __restrict__ A, const unsigned short* __restrict__ B,
        float* __restrict__ Cf, unsigned short* __restrict__ Cb,
        int M, int N, int K, int mode, int NS,
        const float* __restrict__ mul, const float* __restrict__ res) {
    constexpr int BM = 128, BK = 32;
    constexpr int FN = BN / 32;
    __shared__ __align__(16) unsigned short As[BM * BK];
    __shared__ __align__(16) unsigned short Bs[BN * BK];
    const int tid = threadIdx.x;
    const int lane = tid & 63;
    const int w = tid >> 6;
    const int wm = w >> 1, wn = w & 1;
    const int m0 = blockIdx.y * BM, n0 = blockIdx.x * BN;
    const int quad = lane >> 4;
    const int l16 = lane & 15;

    floatx4 acc[4][FN];
    #pragma unroll
    for (int i = 0; i < 4; i++)
        #pragma unroll
        for (int j = 0; j < FN; j++) acc[i][j] = (floatx4){0.f, 0.f, 0.f, 0.f};

    int a_off[4], b_off[FN];
    #pragma unroll
    for (int mi = 0; mi < 4; mi++)
        a_off[mi] = (wm * 64 + mi * 16 + l16) * BK + quad * 8;
    #pragma unroll
    for (int ni = 0; ni < FN; ni++)
        b_off[ni] = (wn * (BN / 2) + ni * 16 + l16) * BK + quad * 8;

    for (int k0 = 0; k0 < K; k0 += BK) {
        const unsigned short* Ag = A + (size_t)m0 * K + k0;
        const unsigned short* Bg = B + (size_t)n0 * K + k0;
        #pragma unroll
        for (int i = 0; i < BM / 64; i++) {
            int c = i * 256 + tid;
            async16(Ag + (size_t)(c >> 2) * K + (c & 3) * 8, As + (i * 256 + w * 64) * 8);
        }
        #pragma unroll
        for (int i = 0; i < BN / 64; i++) {
            int c = i * 256 + tid;
            async16(Bg + (size_t)(c >> 2) * K + (c & 3) * 8, Bs + (i * 256 + w * 64) * 8);
        }
        __syncthreads();
        short8 af[4], bfr[FN];
        #pragma unroll
        for (int mi = 0; mi < 4; mi++) af[mi] = *(const short8*)(As + a_off[mi]);
        #pragma unroll
        for (int ni = 0; ni < FN; ni++) bfr[ni] = *(const short8*)(Bs + b_off[ni]);
        #pragma unroll
        for (int mi = 0; mi < 4; mi++)
            #pragma unroll
            for (int ni = 0; ni < FN; ni++)
                acc[mi][ni] = __builtin_amdgcn_mfma_f32_16x16x32_bf16(af[mi], bfr[ni], acc[mi][ni], 0, 0, 0);
        __syncthreads();
    }

    #pragma unroll
    for (int mi = 0; mi < 4; mi++) {
        #pragma unroll
        for (int ni = 0; ni < FN; ni++) {
            int col = n0 + wn * (BN / 2) + ni * 16 + l16;
            int row0 = m0 + wm * 64 + mi * 16 + quad * 4;
            #pragma unroll
            for (int r = 0; r < 4; r++) {
                float vval = acc[mi][ni][r];
                int row = row0 + r;
                if (mode == 0) {
                    Cf[(size_t)row * N + col] = vval;
                } else if (mode == 1) {
                    size_t off = (size_t)row * N + col;
                    Cf[off] = vval + res[off];
                } else if (mode == 2) {
                    size_t off = (size_t)row * N + col;
                    Cf[off] = vval * mul[off] + res[off];
                } else {
                    if (col < NS) {
                        float tpos = vval > 0.f ? vval : 0.f;
                        Cb[(size_t)row * NS + col] = f2b(tpos * tpos);
                    } else {
                        float sg = 1.f / (1.f + __expf(-vval));
                        Cf[(size_t)row * (N - NS) + (col - NS)] = sg;
                    }
                }
            }
        }
    }
}

// ---------------- WKV sequential scan ----------------
// rkvg layout: [row][3072]: r at +0, k at +768, v at +1536 (g at +2304 unused here)
__global__ __launch_bounds__(256) void wkv_kernel(
        const float* __restrict__ rkvg, const float* __restrict__ bonus,
        const float* __restrict__ decay, float* __restrict__ out) {
    int bh = blockIdx.x;
    int b = bh / HH, h = bh % HH;
    int tid = threadIdx.x;
    int vi = tid & 63;
    int kg = tid >> 6;   // 0..3

    float u_reg[16], w_reg[16], kv[16];
    #pragma unroll
    for (int i = 0; i < 16; i++) {
        int kidx = kg * 16 + i;
        u_reg[i] = bonus[h * KV + kidx];
        w_reg[i] = expf(-expf(decay[h * KV + kidx]));
        kv[i] = 0.f;
    }

    __shared__ float sr[64], sk[64], sred[4][64];

    for (int t = 0; t < TT; t++) {
        size_t base = (size_t)(b * TT + t) * 3072 + h * KV;
        if (tid < 64) sr[tid] = rkvg[base + tid];
        else if (tid < 128) sk[tid - 64] = rkvg[base + 768 + tid - 64];
        float vval = rkvg[base + 1536 + vi];
        __syncthreads();
        float psum = 0.f;
        #pragma unroll
        for (int i = 0; i < 16; i++) {
            float a = sk[kg * 16 + i] * vval;
            psum += sr[kg * 16 + i] * fmaf(u_reg[i], a, kv[i]);
            kv[i] = fmaf(kv[i], w_reg[i], a);
        }
        sred[kg][vi] = psum;
        __syncthreads();
        if (kg == 0)
            out[(size_t)(b * TT + t) * CC + h * KV + vi] =
                sred[0][vi] + sred[1][vi] + sred[2][vi] + sred[3][vi];
    }
}

// ---------------- GroupNorm(eps=0.00064) * silu(g) -> bf16 ----------------
__global__ __launch_bounds__(64) void gn_silu_kernel(
        const float* __restrict__ wkvo, const float* __restrict__ rkvg,
        const float* __restrict__ gs, const float* __restrict__ gb,
        unsigned short* __restrict__ outb) {
    int gi = blockIdx.x;           // row*HH + h
    int vi = threadIdx.x;          // 0..63
    int h = gi % HH;
    int row = gi / HH;
    float val = wkvo[(size_t)gi * 64 + vi];
    float s1 = val;
    #pragma unroll
    for (int off = 32; off >= 1; off >>= 1) s1 += __shfl_xor(s1, off);
    float m = s1 * (1.f / 64.f);
    float d = val - m;
    float s2 = d * d;
    #pragma unroll
    for (int off = 32; off >= 1; off >>= 1) s2 += __shfl_xor(s2, off);
    float inv = rsqrtf(s2 * (1.f / 64.f) + 0.00064f);
    int c = h * 64 + vi;
    float gg = rkvg[(size_t)row * 3072 + 2304 + c];
    float sig = 1.f / (1.f + __expf(-gg));
    outb[(size_t)row * CC + c] = f2b((d * inv * gs[c] + gb[c]) * (gg * sig));
}

// ---------------- host ----------------
extern "C" void kernel_launch(void* const* d_in, const int* in_sizes, int n_in,
                              void* d_out, int out_size, void* d_ws, size_t ws_size,
                              hipStream_t stream) {
    const int*   tokens    = (const int*)  d_in[0];
    const float* embed     = (const float*)d_in[1];
    const float* emb_ln_s  = (const float*)d_in[2];
    const float* emb_ln_b  = (const float*)d_in[3];
    const float* tm_ln_s   = (const float*)d_in[4];
    const float* tm_ln_b   = (const float*)d_in[5];
    const float* ts_r      = (const float*)d_in[6];
    const float* ts_k      = (const float*)d_in[7];
    const float* ts_v      = (const float*)d_in[8];
    const float* ts_g      = (const float*)d_in[9];
    const float* W_r       = (const float*)d_in[10];
    const float* W_k       = (const float*)d_in[11];
    const float* W_v       = (const float*)d_in[12];
    const float* W_g       = (const float*)d_in[13];
    const float* W_o       = (const float*)d_in[14];
    const float* bonus     = (const float*)d_in[15];
    const float* decay     = (const float*)d_in[16];
    const float* gn_s      = (const float*)d_in[17];
    const float* gn_b      = (const float*)d_in[18];
    const float* cm_ln_s   = (const float*)d_in[19];
    const float* cm_ln_b   = (const float*)d_in[20];
    const float* cm_ts_in  = (const float*)d_in[21];
    const float* cm_ts_g   = (const float*)d_in[22];
    const float* W_in      = (const float*)d_in[23];
    const float* W_out     = (const float*)d_in[24];
    const float* W_gate    = (const float*)d_in[25];
    const float* head_ln_s = (const float*)d_in[26];
    const float* head_ln_b = (const float*)d_in[27];
    const float* W_unembed = (const float*)d_in[28];

    char* wsb = (char*)d_ws;
    // fp32 buffers
    float* hbuf = (float*)wsb;                 wsb += (size_t)MM * CC * 4;
    float* lnb  = (float*)wsb;                 wsb += (size_t)MM * CC * 4;
    float* rkvg = (float*)wsb;                 wsb += (size_t)MM * 3072 * 4;
    float* wkvo = (float*)wsb;                 wsb += (size_t)MM * CC * 4;
    float* gate = (float*)wsb;                 wsb += (size_t)MM * CC * 4;
    // bf16 buffers
    unsigned short* abuf   = (unsigned short*)wsb; wsb += (size_t)MM * 1536 * 2;
    unsigned short* tmo_b  = (unsigned short*)wsb; wsb += (size_t)MM * CC * 2;
    unsigned short* hid_b  = (unsigned short*)wsb; wsb += (size_t)MM * DFF * 2;
    unsigned short* lnh_b  = (unsigned short*)wsb; wsb += (size_t)MM * CC * 2;
    unsigned short* Wrkvg_b= (unsigned short*)wsb; wsb += (size_t)3072 * 1536 * 2;
    unsigned short* Wig_b  = (unsigned short*)wsb; wsb += (size_t)3456 * 1536 * 2;
    unsigned short* Wo_b   = (unsigned short*)wsb; wsb += (size_t)CC * CC * 2;
    unsigned short* Wout_b = (unsigned short*)wsb; wsb += (size_t)CC * DFF * 2;
    unsigned short* Wu_b   = (unsigned short*)wsb; wsb += (size_t)VV * CC * 2;

    dim3 b256(256);
    const int n4_cc = CC * CC / 4;        // 147456
    const int n4_ff = DFF * CC / 4;       // 516096
    const int n4_un = VV * CC / 4;        // 9658368

    // embedding + LN
    ln_kernel<<<dim3(MM), b256, 0, stream>>>(embed, tokens, emb_ln_s, emb_ln_b, hbuf, nullptr);

    for (int l = 0; l < LL; l++) {
        const float* Wr = W_r + (size_t)l * CC * CC;
        const float* Wk = W_k + (size_t)l * CC * CC;
        const float* Wv = W_v + (size_t)l * CC * CC;
        const float* Wg = W_g + (size_t)l * CC * CC;
        const float* Wo = W_o + (size_t)l * CC * CC;
        const float* Wi = W_in  + (size_t)l * DFF * CC;
        const float* Wu = W_out + (size_t)l * CC * DFF;
        const float* Wgt= W_gate+ (size_t)l * CC * CC;

        // ---- time mixer ----
        // pack W_{r,k,v,g} (lerp-folded) into Wrkvg_b [3072][1536]
        packw_kernel<<<dim3((n4_cc + 255) / 256), b256, 0, stream>>>(Wr, ts_r + l*CC, Wrkvg_b,                        CC, n4_cc);
        packw_kernel<<<dim3((n4_cc + 255) / 256), b256, 0, stream>>>(Wk, ts_k + l*CC, Wrkvg_b + (size_t) 768 * 1536, CC, n4_cc);
        packw_kernel<<<dim3((n4_cc + 255) / 256), b256, 0, stream>>>(Wv, ts_v + l*CC, Wrkvg_b + (size_t)1536 * 1536, CC, n4_cc);
        packw_kernel<<<dim3((n4_cc + 255) / 256), b256, 0, stream>>>(Wg, ts_g + l*CC, Wrkvg_b + (size_t)2304 * 1536, CC, n4_cc);
        convertw_kernel<<<dim3((n4_cc + 255) / 256), b256, 0, stream>>>(Wo, Wo_b, n4_cc);

        ln_kernel<<<dim3(MM), b256, 0, stream>>>(hbuf, nullptr, tm_ln_s + l*CC, tm_ln_b + l*CC, lnb, nullptr);
        build_a_kernel<<<dim3(MM * 192 / 256), b256, 0, stream>>>(lnb, abuf);
        // rkvg = [x,xs] @ Wrkvg^T : M=1024, N=3072, K=1536
        mfma_gemm_kernel<128><<<dim3(3072/128, MM/128), b256, 0, stream>>>(
            abuf, Wrkvg_b, rkvg, nullptr, MM, 3072, 1536, 0, 0, nullptr, nullptr);
        wkv_kernel<<<dim3(BB*HH), b256, 0, stream>>>(rkvg, bonus + l*HH*KV, decay + l*HH*KV, wkvo);
        gn_silu_kernel<<<dim3(MM*HH), dim3(64), 0, stream>>>(wkvo, rkvg, gn_s + l*CC, gn_b + l*CC, tmo_b);
        // h += tmo @ Wo^T : N=768, K=768 (BN=64 for occupancy)
        mfma_gemm_kernel<64><<<dim3(CC/64, MM/128), b256, 0, stream>>>(
            tmo_b, Wo_b, hbuf, nullptr, MM, CC, CC, 1, 0, nullptr, hbuf);

        // ---- channel mixer ----
        packw_kernel<<<dim3((n4_ff + 255) / 256), b256, 0, stream>>>(Wi,  cm_ts_in + l*CC, Wig_b,                       CC, n4_ff);
        packw_kernel<<<dim3((n4_cc + 255) / 256), b256, 0, stream>>>(Wgt, cm_ts_g  + l*CC, Wig_b + (size_t)DFF * 1536, CC, n4_cc);
        convertw_kernel<<<dim3((n4_ff + 255) / 256), b256, 0, stream>>>(Wu, Wout_b, n4_ff);

        ln_kernel<<<dim3(MM), b256, 0, stream>>>(hbuf, nullptr, cm_ln_s + l*CC, cm_ln_b + l*CC, lnb, nullptr);
        build_a_kernel<<<dim3(MM * 192 / 256), b256, 0, stream>>>(lnb, abuf);
        // [hid | gate] = [x,xs] @ Wig^T : N=3456, K=1536, split epilogue at NS=2688
        mfma_gemm_kernel<128><<<dim3(3456/128, MM/128), b256, 0, stream>>>(
            abuf, Wig_b, gate, hid_b, MM, 3456, 1536, 3, DFF, nullptr, nullptr);
        // h += (hid @ Wout^T) * gate : N=768, K=2688
        mfma_gemm_kernel<64><<<dim3(CC/64, MM/128), b256, 0, stream>>>(
            hid_b, Wout_b, hbuf, nullptr, MM, CC, DFF, 2, 0, gate, hbuf);
    }

    // head LN + unembed
    ln_kernel<<<dim3(MM), b256, 0, stream>>>(hbuf, nullptr, head_ln_s, head_ln_b, lnb, lnh_b);
    convertw_kernel<<<dim3((n4_un + 255) / 256), b256, 0, stream>>>(W_unembed, Wu_b, n4_un);
    mfma_gemm_kernel<128><<<dim3(VV/128, MM/128), b256, 0, stream>>>(
        lnh_b, Wu_b, (float*)d_out, nullptr, MM, VV, CC, 0, 0, nullptr, nullptr);
}